// Round 11
// baseline (330.982 us; speedup 1.0000x reference)
//
#include <hip/hip_runtime.h>
#include <math.h>

// Problem constants
#define NBATCH 4096      // BS*T
#define NAG    16        // N agents
#define UDIM   32
#define SDIM   560
#define HN     4
#define EDIM   32
#define GHD    64
#define WCOLS  192       // 128 sel + 32 V-hidden + 4 wh + 28 pad
#define NEGV   -99999999.0f
#define COEF   0.001f

// workspace layout (float offsets)
#define WS_WCAT  0                          // [560][192] transposed weight panel
#define WS_W1T   (SDIM*WCOLS)               // [64][64]  g_W1 transposed
#define WS_P     (WS_W1T + 64*64)           // [4096][192] per-row projections
#define WS_PART  (WS_P + NBATCH*WCOLS)      // [4096][8] partial sums (sumsq, ent[4])

// ---------------------------------------------------------------------------
// k0: build transposed weight panel WcatT[s][c] and W1T[k][g]
__global__ void k0_prep(const float* __restrict__ sel_W,
                        const float* __restrict__ V_W1,
                        const float* __restrict__ wh_W,
                        const float* __restrict__ g_W1,
                        float* __restrict__ ws) {
    int idx = blockIdx.x * 256 + threadIdx.x;
    if (idx < SDIM * WCOLS) {
        int s = idx / WCOLS, c = idx - s * WCOLS;
        float v = 0.f;
        if (c < 128)      v = sel_W[c * SDIM + s];
        else if (c < 160) v = V_W1[(c - 128) * SDIM + s];
        else if (c < 164) v = wh_W[(c - 160) * SDIM + s];
        ws[WS_WCAT + idx] = v;
    } else {
        int i2 = idx - SDIM * WCOLS;
        if (i2 < 64 * 64) {
            int k = i2 >> 6, g = i2 & 63;
            ws[WS_W1T + i2] = g_W1[g * 64 + k];   // W1T[k][g]
        }
    }
}

// ---------------------------------------------------------------------------
// k1: P[4096][192] = states[4096][560] @ WcatT   (skinny GEMM, 16-row tiles)
#define K1_ROWS 16
#define K1_KC   56
__global__ __launch_bounds__(256) void k1_gemm(const float* __restrict__ states,
                                               const float* __restrict__ ws,
                                               float* __restrict__ wsP) {
    __shared__ float As[K1_ROWS][K1_KC + 1];              // +1 pad: bank-safe
    __shared__ __align__(16) float Bs[K1_KC * WCOLS];     // 43 KB
    const float* wcatT = &ws[WS_WCAT];
    int tid = threadIdx.x;
    int b0  = blockIdx.x * K1_ROWS;
    int r   = tid >> 4;       // 0..15 row
    int cg  = tid & 15;       // 0..15 col group (12 cols each)
    float acc[12];
#pragma unroll
    for (int j = 0; j < 12; ++j) acc[j] = 0.f;

    for (int ks = 0; ks < SDIM; ks += K1_KC) {
        {   // stage A tile: 16 rows x 56
            int rr = tid >> 4, kk = tid & 15;
            for (int k2 = kk; k2 < K1_KC; k2 += 16)
                As[rr][k2] = states[(b0 + rr) * SDIM + ks + k2];
        }
        // stage B tile: contiguous 56*192 floats, float4 loads
        for (int i = tid * 4; i < K1_KC * WCOLS; i += 256 * 4) {
            float4 v = *reinterpret_cast<const float4*>(&wcatT[ks * WCOLS + i]);
            *reinterpret_cast<float4*>(&Bs[i]) = v;
        }
        __syncthreads();
#pragma unroll 4
        for (int kk = 0; kk < K1_KC; ++kk) {
            float a = As[r][kk];
            const float* bp = &Bs[kk * WCOLS + cg * 12];
#pragma unroll
            for (int j = 0; j < 12; ++j) acc[j] += a * bp[j];
        }
        __syncthreads();
    }
    float* outp = &wsP[WS_P + (b0 + r) * WCOLS + cg * 12];
#pragma unroll
    for (int j = 0; j < 12; ++j) outp[j] = acc[j];
}

// ---------------------------------------------------------------------------
// k2: one block per batch row. proj/logits/softmax, graph MLP, adjacency,
//     renorm, q_tot, adj output, partial sums for scalars.
// v3: pin waves/EU to (4,4) so the allocator stops shrinking to 8-waves/EU
//     occupancy (which spilled h1v at VGPR=44 in v2). Budget is 128 VGPR;
//     h1 (64 floats) + working set fits. Everything else identical to v2.
__global__ __attribute__((amdgpu_waves_per_eu(4, 4)))
__launch_bounds__(256) void k2_main(
    const float* __restrict__ agent_qs,
    const float* __restrict__ states,
    const int*   __restrict__ actions,
    const float* __restrict__ key_W,
    const float* __restrict__ wh_b,
    const float* __restrict__ V_b1,
    const float* __restrict__ V_W2,
    const float* __restrict__ V_b2,
    const float* __restrict__ g_b1,
    const float* __restrict__ g_W2,
    const float* __restrict__ g_b2,
    const float* __restrict__ g_W3,
    const float* __restrict__ g_b3,
    float* __restrict__ ws,
    float* __restrict__ out)
{
    const int b   = blockIdx.x;
    const int tid = threadIdx.x;

    __shared__ float unit_s[NAG * 33];               // padded stride 33
    __shared__ float sel_s[128];
    __shared__ float proj_s[HN * 33];
    __shared__ float attw_s[64];
    __shared__ __align__(16) float As[NAG * 68];     // stride 68 floats (16B ok)
    __shared__ __align__(16) float Bsh[NAG * 68];
    __shared__ float b1s[GHD];
    __shared__ float adjmean_s[NAG];
    __shared__ float qs_s[NAG];
    __shared__ float red_s[256];

    // ---- stage
    for (int i = tid; i < NAG * UDIM; i += 256)
        unit_s[(i >> 5) * 33 + (i & 31)] = states[b * SDIM + i];
    if (tid < 128) sel_s[tid] = ws[WS_P + b * WCOLS + tid];
    if (tid < GHD) b1s[tid] = g_b1[tid];
    if (tid < NAG) qs_s[tid] = agent_qs[b * NAG + tid];
    __syncthreads();

    // ---- proj[h][u] = sum_e sel[h,e] * key_W[h,e,u]
    if (tid < 128) {
        int h = tid >> 5, u = tid & 31;
        float a = 0.f;
#pragma unroll
        for (int e = 0; e < EDIM; ++e)
            a += sel_s[h * EDIM + e] * key_W[(h * EDIM + e) * UDIM + u];
        proj_s[h * 33 + u] = a;
    }
    // ---- A[i][g] = u_i . W1a[g] + b1[g] ;  B[j][g] = u_j . W1b[g]
    {
        const float* W1T = &ws[WS_W1T];
        for (int o = tid; o < 2 * NAG * GHD; o += 256) {
            int which = o >> 10;          // 0=A, 1=B
            int i = (o >> 6) & 15;
            int g = o & 63;
            float a = 0.f;
#pragma unroll
            for (int u = 0; u < UDIM; ++u)
                a += unit_s[i * 33 + u] * W1T[(which * UDIM + u) * 64 + g];
            if (which == 0) As[i * 68 + g] = a + b1s[g];
            else            Bsh[i * 68 + g] = a;
        }
    }
    __syncthreads();

    // ---- wave 0: logits + reg sumsq + masked softmax
    if (tid < 64) {
        int n = tid & 15;
        int h = tid >> 4;
        float l = 0.f;
#pragma unroll
        for (int u = 0; u < UDIM; ++u)
            l += proj_s[h * 33 + u] * unit_s[n * 33 + u];
        float sq = l * l;
#pragma unroll
        for (int m = 1; m < 64; m <<= 1) sq += __shfl_xor(sq, m, 64);
        if (tid == 0) ws[WS_PART + b * 8 + 0] = sq;
        float sc = l * 0.17677669529663688f;          // 1/sqrt(32)
        if (actions[b * NAG + n] == 0) sc = NEGV;
        float mx = sc;
#pragma unroll
        for (int m = 1; m < 16; m <<= 1) mx = fmaxf(mx, __shfl_xor(mx, m, 16));
        float ex = expf(sc - mx);
        float sm = ex;
#pragma unroll
        for (int m = 1; m < 16; m <<= 1) sm += __shfl_xor(sm, m, 16);
        attw_s[tid] = ex / sm;
    }

    // ---- pair loop: one (i,j) per thread; h1 in registers
    {
        int i = tid >> 4, j = tid & 15;
        const float4* Ap = reinterpret_cast<const float4*>(&As[i * 68]);
        const float4* Bp = reinterpret_cast<const float4*>(&Bsh[j * 68]);
        float4 h1v[16];
#pragma unroll
        for (int q = 0; q < 16; ++q) {
            float4 av = Ap[q], bv = Bp[q];
            h1v[q].x = fmaxf(av.x + bv.x, 0.f);
            h1v[q].y = fmaxf(av.y + bv.y, 0.f);
            h1v[q].z = fmaxf(av.z + bv.z, 0.f);
            h1v[q].w = fmaxf(av.w + bv.w, 0.f);
        }
        float el = g_b3[0];
#pragma unroll 2
        for (int g2 = 0; g2 < GHD; ++g2) {
            const float* w = &g_W2[g2 * GHD];   // wave-uniform -> s_load
            float a0 = 0.f, a1 = 0.f, a2 = 0.f, a3 = 0.f;
#pragma unroll
            for (int q = 0; q < 16; ++q) {
                a0 += h1v[q].x * w[q * 4 + 0];
                a1 += h1v[q].y * w[q * 4 + 1];
                a2 += h1v[q].z * w[q * 4 + 2];
                a3 += h1v[q].w * w[q * 4 + 3];
            }
            float a = ((a0 + a1) + (a2 + a3)) + g_b2[g2];
            el += fmaxf(a, 0.f) * g_W3[g2];
        }
        float adjv = 1.f / (1.f + expf(-el));
        if (i == j) adjv += 1.f;
        out[4101 + b * 256 + tid] = adjv;   // adj output
        red_s[tid] = adjv;
    }
    __syncthreads();

    // ---- adj_mean[j] = mean_i adj[i][j]
    if (tid < NAG) {
        float s = 0.f;
#pragma unroll
        for (int i = 0; i < NAG; ++i) s += red_s[i * NAG + tid];
        adjmean_s[tid] = s * (1.0f / 16.0f);
    }
    __syncthreads();

    // ---- renorm, head_q, entropy, q_tot pieces
    if (tid < 64) {
        int n = tid & 15;
        int h = tid >> 4;
        float a = attw_s[tid] * adjmean_s[n];
        float s = a;
#pragma unroll
        for (int m = 1; m < 16; m <<= 1) s += __shfl_xor(s, m, 16);
        float adjw = a / (s + 1e-8f);
        float hq  = qs_s[n] * adjw;
        float ent = -logf(adjw + 1e-8f) * adjw;
#pragma unroll
        for (int m = 1; m < 16; m <<= 1) {
            hq  += __shfl_xor(hq, m, 16);
            ent += __shfl_xor(ent, m, 16);
        }
        if (n == 0) {
            float wh = fabsf(ws[WS_P + b * WCOLS + 160 + h] + wh_b[h]);
            red_s[h] = wh * hq;
            ws[WS_PART + b * 8 + 1 + h] = ent;
        }
    }
    __syncthreads();
    if (tid == 0) {
        float v = V_b2[0];
#pragma unroll
        for (int e = 0; e < EDIM; ++e)
            v += fmaxf(ws[WS_P + b * WCOLS + 128 + e] + V_b1[e], 0.f) * V_W2[e];
        out[b] = red_s[0] + red_s[1] + red_s[2] + red_s[3] + v;
    }
}

// ---------------------------------------------------------------------------
// k3: deterministic final reduction of partials -> attend_mag_regs, head_entropies
__global__ __launch_bounds__(256) void k3_final(const float* __restrict__ ws,
                                                float* __restrict__ out) {
    __shared__ float red[4][5];
    int tid = threadIdx.x;
    float acc[5] = {0.f, 0.f, 0.f, 0.f, 0.f};
    for (int r = tid; r < NBATCH; r += 256) {
        const float* p = &ws[WS_PART + r * 8];
#pragma unroll
        for (int j = 0; j < 5; ++j) acc[j] += p[j];
    }
#pragma unroll
    for (int j = 0; j < 5; ++j) {
        float v = acc[j];
#pragma unroll
        for (int m = 1; m < 64; m <<= 1) v += __shfl_xor(v, m, 64);
        if ((tid & 63) == 0) red[tid >> 6][j] = v;
    }
    __syncthreads();
    if (tid == 0) {
        float s0 = red[0][0] + red[1][0] + red[2][0] + red[3][0];
        out[4096] = s0 * (COEF / 65536.0f);          // mean over B*N, sum over H
#pragma unroll
        for (int h = 0; h < 4; ++h) {
            float s = red[0][1 + h] + red[1][1 + h] + red[2][1 + h] + red[3][1 + h];
            out[4097 + h] = s * (1.0f / 4096.0f);    // mean over B
        }
    }
}

// ---------------------------------------------------------------------------
extern "C" void kernel_launch(void* const* d_in, const int* in_sizes, int n_in,
                              void* d_out, int out_size, void* d_ws, size_t ws_size,
                              hipStream_t stream) {
    const float* agent_qs = (const float*)d_in[0];
    const float* states   = (const float*)d_in[1];
    const int*   actions  = (const int*)  d_in[2];
    const float* sel_W    = (const float*)d_in[3];
    const float* key_W    = (const float*)d_in[4];
    const float* wh_W     = (const float*)d_in[5];
    const float* wh_b     = (const float*)d_in[6];
    const float* V_W1     = (const float*)d_in[7];
    const float* V_b1     = (const float*)d_in[8];
    const float* V_W2     = (const float*)d_in[9];
    const float* V_b2     = (const float*)d_in[10];
    const float* g_W1     = (const float*)d_in[11];
    const float* g_b1     = (const float*)d_in[12];
    const float* g_W2     = (const float*)d_in[13];
    const float* g_b2     = (const float*)d_in[14];
    const float* g_W3     = (const float*)d_in[15];
    const float* g_b3     = (const float*)d_in[16];

    float* ws  = (float*)d_ws;
    float* out = (float*)d_out;

    // k0: weight transposes (111,616 elements)
    k0_prep<<<436, 256, 0, stream>>>(sel_W, V_W1, wh_W, g_W1, ws);
    // k1: skinny GEMM [4096,560]x[560,192]
    k1_gemm<<<NBATCH / K1_ROWS, 256, 0, stream>>>(states, ws, ws);
    // k2: per-row fused mixer + graph MLP
    k2_main<<<NBATCH, 256, 0, stream>>>(agent_qs, states, actions, key_W,
                                        wh_b, V_b1, V_W2, V_b2,
                                        g_b1, g_W2, g_b2, g_W3, g_b3,
                                        ws, out);
    // k3: scalar outputs
    k3_final<<<1, 256, 0, stream>>>(ws, out);
}

// Round 12
// 330.398 us; speedup vs baseline: 1.0018x; 1.0018x over previous
//
#include <hip/hip_runtime.h>
#include <math.h>

// Problem constants
#define NBATCH 4096      // BS*T
#define NAG    16        // N agents
#define UDIM   32
#define SDIM   560
#define HN     4
#define EDIM   32
#define GHD    64
#define WCOLS  192       // 128 sel + 32 V-hidden + 4 wh + 28 pad
#define NEGV   -99999999.0f
#define COEF   0.001f

// workspace layout (float offsets)
#define WS_WCAT  0                          // [560][192] transposed weight panel
#define WS_W1T   (SDIM*WCOLS)               // [64][64]  g_W1 transposed
#define WS_P     (WS_W1T + 64*64)           // [4096][192] per-row projections
#define WS_PART  (WS_P + NBATCH*WCOLS)      // [4096][8] partial sums (sumsq, ent[4])

// ---------------------------------------------------------------------------
// k0: build transposed weight panel WcatT[s][c] and W1T[k][g]
__global__ void k0_prep(const float* __restrict__ sel_W,
                        const float* __restrict__ V_W1,
                        const float* __restrict__ wh_W,
                        const float* __restrict__ g_W1,
                        float* __restrict__ ws) {
    int idx = blockIdx.x * 256 + threadIdx.x;
    if (idx < SDIM * WCOLS) {
        int s = idx / WCOLS, c = idx - s * WCOLS;
        float v = 0.f;
        if (c < 128)      v = sel_W[c * SDIM + s];
        else if (c < 160) v = V_W1[(c - 128) * SDIM + s];
        else if (c < 164) v = wh_W[(c - 160) * SDIM + s];
        ws[WS_WCAT + idx] = v;
    } else {
        int i2 = idx - SDIM * WCOLS;
        if (i2 < 64 * 64) {
            int k = i2 >> 6, g = i2 & 63;
            ws[WS_W1T + i2] = g_W1[g * 64 + k];   // W1T[k][g]
        }
    }
}

// ---------------------------------------------------------------------------
// k1: P[4096][192] = states[4096][560] @ WcatT   (skinny GEMM, 16-row tiles)
#define K1_ROWS 16
#define K1_KC   56
__global__ __launch_bounds__(256) void k1_gemm(const float* __restrict__ states,
                                               const float* __restrict__ ws,
                                               float* __restrict__ wsP) {
    __shared__ float As[K1_ROWS][K1_KC + 1];              // +1 pad: bank-safe
    __shared__ __align__(16) float Bs[K1_KC * WCOLS];     // 43 KB
    const float* wcatT = &ws[WS_WCAT];
    int tid = threadIdx.x;
    int b0  = blockIdx.x * K1_ROWS;
    int r   = tid >> 4;       // 0..15 row
    int cg  = tid & 15;       // 0..15 col group (12 cols each)
    float acc[12];
#pragma unroll
    for (int j = 0; j < 12; ++j) acc[j] = 0.f;

    for (int ks = 0; ks < SDIM; ks += K1_KC) {
        {   // stage A tile: 16 rows x 56
            int rr = tid >> 4, kk = tid & 15;
            for (int k2 = kk; k2 < K1_KC; k2 += 16)
                As[rr][k2] = states[(b0 + rr) * SDIM + ks + k2];
        }
        // stage B tile: contiguous 56*192 floats, float4 loads
        for (int i = tid * 4; i < K1_KC * WCOLS; i += 256 * 4) {
            float4 v = *reinterpret_cast<const float4*>(&wcatT[ks * WCOLS + i]);
            *reinterpret_cast<float4*>(&Bs[i]) = v;
        }
        __syncthreads();
#pragma unroll 4
        for (int kk = 0; kk < K1_KC; ++kk) {
            float a = As[r][kk];
            const float* bp = &Bs[kk * WCOLS + cg * 12];
#pragma unroll
            for (int j = 0; j < 12; ++j) acc[j] += a * bp[j];
        }
        __syncthreads();
    }
    float* outp = &wsP[WS_P + (b0 + r) * WCOLS + cg * 12];
#pragma unroll
    for (int j = 0; j < 12; ++j) outp[j] = acc[j];
}

// ---------------------------------------------------------------------------
// k2: one block per batch row. proj/logits/softmax, graph MLP, adjacency,
//     renorm, q_tot, adj output, partial sums for scalars.
// v4: h1 forced into VGPRs via opaque asm keep-alive (defeats LLVM's
//     LDS-rematerialization, the real cause of v2/v3's VGPR=44/52 and
//     LDS-issue-bound g2 loop). waves_per_eu(4,4) kept ONLY as the
//     128-VGPR cap so the forced liveness doesn't spill.
__global__ __attribute__((amdgpu_waves_per_eu(4, 4)))
__launch_bounds__(256) void k2_main(
    const float* __restrict__ agent_qs,
    const float* __restrict__ states,
    const int*   __restrict__ actions,
    const float* __restrict__ key_W,
    const float* __restrict__ wh_b,
    const float* __restrict__ V_b1,
    const float* __restrict__ V_W2,
    const float* __restrict__ V_b2,
    const float* __restrict__ g_b1,
    const float* __restrict__ g_W2,
    const float* __restrict__ g_b2,
    const float* __restrict__ g_W3,
    const float* __restrict__ g_b3,
    float* __restrict__ ws,
    float* __restrict__ out)
{
    const int b   = blockIdx.x;
    const int tid = threadIdx.x;

    __shared__ float unit_s[NAG * 33];               // padded stride 33
    __shared__ float sel_s[128];
    __shared__ float proj_s[HN * 33];
    __shared__ float attw_s[64];
    __shared__ __align__(16) float As[NAG * 68];     // stride 68 floats (16B ok)
    __shared__ __align__(16) float Bsh[NAG * 68];
    __shared__ float b1s[GHD];
    __shared__ float adjmean_s[NAG];
    __shared__ float qs_s[NAG];
    __shared__ float red_s[256];

    // ---- stage
    for (int i = tid; i < NAG * UDIM; i += 256)
        unit_s[(i >> 5) * 33 + (i & 31)] = states[b * SDIM + i];
    if (tid < 128) sel_s[tid] = ws[WS_P + b * WCOLS + tid];
    if (tid < GHD) b1s[tid] = g_b1[tid];
    if (tid < NAG) qs_s[tid] = agent_qs[b * NAG + tid];
    __syncthreads();

    // ---- proj[h][u] = sum_e sel[h,e] * key_W[h,e,u]
    if (tid < 128) {
        int h = tid >> 5, u = tid & 31;
        float a = 0.f;
#pragma unroll
        for (int e = 0; e < EDIM; ++e)
            a += sel_s[h * EDIM + e] * key_W[(h * EDIM + e) * UDIM + u];
        proj_s[h * 33 + u] = a;
    }
    // ---- A[i][g] = u_i . W1a[g] + b1[g] ;  B[j][g] = u_j . W1b[g]
    {
        const float* W1T = &ws[WS_W1T];
        for (int o = tid; o < 2 * NAG * GHD; o += 256) {
            int which = o >> 10;          // 0=A, 1=B
            int i = (o >> 6) & 15;
            int g = o & 63;
            float a = 0.f;
#pragma unroll
            for (int u = 0; u < UDIM; ++u)
                a += unit_s[i * 33 + u] * W1T[(which * UDIM + u) * 64 + g];
            if (which == 0) As[i * 68 + g] = a + b1s[g];
            else            Bsh[i * 68 + g] = a;
        }
    }
    __syncthreads();

    // ---- wave 0: logits + reg sumsq + masked softmax
    if (tid < 64) {
        int n = tid & 15;
        int h = tid >> 4;
        float l = 0.f;
#pragma unroll
        for (int u = 0; u < UDIM; ++u)
            l += proj_s[h * 33 + u] * unit_s[n * 33 + u];
        float sq = l * l;
#pragma unroll
        for (int m = 1; m < 64; m <<= 1) sq += __shfl_xor(sq, m, 64);
        if (tid == 0) ws[WS_PART + b * 8 + 0] = sq;
        float sc = l * 0.17677669529663688f;          // 1/sqrt(32)
        if (actions[b * NAG + n] == 0) sc = NEGV;
        float mx = sc;
#pragma unroll
        for (int m = 1; m < 16; m <<= 1) mx = fmaxf(mx, __shfl_xor(mx, m, 16));
        float ex = expf(sc - mx);
        float sm = ex;
#pragma unroll
        for (int m = 1; m < 16; m <<= 1) sm += __shfl_xor(sm, m, 16);
        attw_s[tid] = ex / sm;
    }

    // ---- pair loop: one (i,j) per thread; h1 pinned in registers
    {
        int i = tid >> 4, j = tid & 15;
        const float4* Ap = reinterpret_cast<const float4*>(&As[i * 68]);
        const float4* Bp = reinterpret_cast<const float4*>(&Bsh[j * 68]);
        float h1r[GHD];
#pragma unroll
        for (int q = 0; q < 16; ++q) {
            float4 av = Ap[q], bv = Bp[q];
            h1r[q * 4 + 0] = fmaxf(av.x + bv.x, 0.f);
            h1r[q * 4 + 1] = fmaxf(av.y + bv.y, 0.f);
            h1r[q * 4 + 2] = fmaxf(av.z + bv.z, 0.f);
            h1r[q * 4 + 3] = fmaxf(av.w + bv.w, 0.f);
        }
        // Opaque def: compiler cannot rematerialize h1 from LDS past this.
#pragma unroll
        for (int g = 0; g < GHD; ++g)
            asm volatile("" : "+v"(h1r[g]));

        float el = g_b3[0];
#pragma unroll 2
        for (int g2 = 0; g2 < GHD; ++g2) {
            const float* w = &g_W2[g2 * GHD];   // wave-uniform -> s_load
            float a0 = 0.f, a1 = 0.f, a2 = 0.f, a3 = 0.f;
#pragma unroll
            for (int g = 0; g < GHD; g += 4) {
                a0 += h1r[g + 0] * w[g + 0];
                a1 += h1r[g + 1] * w[g + 1];
                a2 += h1r[g + 2] * w[g + 2];
                a3 += h1r[g + 3] * w[g + 3];
            }
            float a = ((a0 + a1) + (a2 + a3)) + g_b2[g2];
            el += fmaxf(a, 0.f) * g_W3[g2];
        }
        float adjv = 1.f / (1.f + expf(-el));
        if (i == j) adjv += 1.f;
        out[4101 + b * 256 + tid] = adjv;   // adj output
        red_s[tid] = adjv;
    }
    __syncthreads();

    // ---- adj_mean[j] = mean_i adj[i][j]
    if (tid < NAG) {
        float s = 0.f;
#pragma unroll
        for (int i = 0; i < NAG; ++i) s += red_s[i * NAG + tid];
        adjmean_s[tid] = s * (1.0f / 16.0f);
    }
    __syncthreads();

    // ---- renorm, head_q, entropy, q_tot pieces
    if (tid < 64) {
        int n = tid & 15;
        int h = tid >> 4;
        float a = attw_s[tid] * adjmean_s[n];
        float s = a;
#pragma unroll
        for (int m = 1; m < 16; m <<= 1) s += __shfl_xor(s, m, 16);
        float adjw = a / (s + 1e-8f);
        float hq  = qs_s[n] * adjw;
        float ent = -logf(adjw + 1e-8f) * adjw;
#pragma unroll
        for (int m = 1; m < 16; m <<= 1) {
            hq  += __shfl_xor(hq, m, 16);
            ent += __shfl_xor(ent, m, 16);
        }
        if (n == 0) {
            float wh = fabsf(ws[WS_P + b * WCOLS + 160 + h] + wh_b[h]);
            red_s[h] = wh * hq;
            ws[WS_PART + b * 8 + 1 + h] = ent;
        }
    }
    __syncthreads();
    if (tid == 0) {
        float v = V_b2[0];
#pragma unroll
        for (int e = 0; e < EDIM; ++e)
            v += fmaxf(ws[WS_P + b * WCOLS + 128 + e] + V_b1[e], 0.f) * V_W2[e];
        out[b] = red_s[0] + red_s[1] + red_s[2] + red_s[3] + v;
    }
}

// ---------------------------------------------------------------------------
// k3: deterministic final reduction of partials -> attend_mag_regs, head_entropies
__global__ __launch_bounds__(256) void k3_final(const float* __restrict__ ws,
                                                float* __restrict__ out) {
    __shared__ float red[4][5];
    int tid = threadIdx.x;
    float acc[5] = {0.f, 0.f, 0.f, 0.f, 0.f};
    for (int r = tid; r < NBATCH; r += 256) {
        const float* p = &ws[WS_PART + r * 8];
#pragma unroll
        for (int j = 0; j < 5; ++j) acc[j] += p[j];
    }
#pragma unroll
    for (int j = 0; j < 5; ++j) {
        float v = acc[j];
#pragma unroll
        for (int m = 1; m < 64; m <<= 1) v += __shfl_xor(v, m, 64);
        if ((tid & 63) == 0) red[tid >> 6][j] = v;
    }
    __syncthreads();
    if (tid == 0) {
        float s0 = red[0][0] + red[1][0] + red[2][0] + red[3][0];
        out[4096] = s0 * (COEF / 65536.0f);          // mean over B*N, sum over H
#pragma unroll
        for (int h = 0; h < 4; ++h) {
            float s = red[0][1 + h] + red[1][1 + h] + red[2][1 + h] + red[3][1 + h];
            out[4097 + h] = s * (1.0f / 4096.0f);    // mean over B
        }
    }
}

// ---------------------------------------------------------------------------
extern "C" void kernel_launch(void* const* d_in, const int* in_sizes, int n_in,
                              void* d_out, int out_size, void* d_ws, size_t ws_size,
                              hipStream_t stream) {
    const float* agent_qs = (const float*)d_in[0];
    const float* states   = (const float*)d_in[1];
    const int*   actions  = (const int*)  d_in[2];
    const float* sel_W    = (const float*)d_in[3];
    const float* key_W    = (const float*)d_in[4];
    const float* wh_W     = (const float*)d_in[5];
    const float* wh_b     = (const float*)d_in[6];
    const float* V_W1     = (const float*)d_in[7];
    const float* V_b1     = (const float*)d_in[8];
    const float* V_W2     = (const float*)d_in[9];
    const float* V_b2     = (const float*)d_in[10];
    const float* g_W1     = (const float*)d_in[11];
    const float* g_b1     = (const float*)d_in[12];
    const float* g_W2     = (const float*)d_in[13];
    const float* g_b2     = (const float*)d_in[14];
    const float* g_W3     = (const float*)d_in[15];
    const float* g_b3     = (const float*)d_in[16];

    float* ws  = (float*)d_ws;
    float* out = (float*)d_out;

    // k0: weight transposes (111,616 elements)
    k0_prep<<<436, 256, 0, stream>>>(sel_W, V_W1, wh_W, g_W1, ws);
    // k1: skinny GEMM [4096,560]x[560,192]
    k1_gemm<<<NBATCH / K1_ROWS, 256, 0, stream>>>(states, ws, ws);
    // k2: per-row fused mixer + graph MLP
    k2_main<<<NBATCH, 256, 0, stream>>>(agent_qs, states, actions, key_W,
                                        wh_b, V_b1, V_W2, V_b2,
                                        g_b1, g_W2, g_b2, g_W3, g_b3,
                                        ws, out);
    // k3: scalar outputs
    k3_final<<<1, 256, 0, stream>>>(ws, out);
}

// Round 16
// 243.165 us; speedup vs baseline: 1.3611x; 1.3587x over previous
//
#include <hip/hip_runtime.h>
#include <math.h>

// Problem constants
#define NBATCH 4096      // BS*T
#define NAG    16        // N agents
#define UDIM   32
#define SDIM   560
#define HN     4
#define EDIM   32
#define GHD    64
#define WCOLS  192       // 128 sel + 32 V-hidden + 4 wh + 28 pad
#define NEGV   -99999999.0f
#define COEF   0.001f

// workspace layout (float offsets)
#define WS_WCAT  0                          // [560][192] transposed weight panel
#define WS_W1T   (SDIM*WCOLS)               // [64][64]  g_W1 transposed
#define WS_P     (WS_W1T + 64*64)           // [4096][192] per-row projections
#define WS_PART  (WS_P + NBATCH*WCOLS)      // [4096][8] partial sums (sumsq, ent[4])

typedef short bf16x8 __attribute__((ext_vector_type(8)));
typedef float f32x4  __attribute__((ext_vector_type(4)));

// ---------------------------------------------------------------------------
// k0: build transposed weight panel WcatT[s][c] and W1T[k][g]
__global__ void k0_prep(const float* __restrict__ sel_W,
                        const float* __restrict__ V_W1,
                        const float* __restrict__ wh_W,
                        const float* __restrict__ g_W1,
                        float* __restrict__ ws) {
    int idx = blockIdx.x * 256 + threadIdx.x;
    if (idx < SDIM * WCOLS) {
        int s = idx / WCOLS, c = idx - s * WCOLS;
        float v = 0.f;
        if (c < 128)      v = sel_W[c * SDIM + s];
        else if (c < 160) v = V_W1[(c - 128) * SDIM + s];
        else if (c < 164) v = wh_W[(c - 160) * SDIM + s];
        ws[WS_WCAT + idx] = v;
    } else {
        int i2 = idx - SDIM * WCOLS;
        if (i2 < 64 * 64) {
            int k = i2 >> 6, g = i2 & 63;
            ws[WS_W1T + i2] = g_W1[g * 64 + k];   // W1T[k][g]
        }
    }
}

// ---------------------------------------------------------------------------
// k1: P[4096][192] = states[4096][560] @ WcatT   (skinny GEMM, 16-row tiles)
#define K1_ROWS 16
#define K1_KC   56
__global__ __launch_bounds__(256) void k1_gemm(const float* __restrict__ states,
                                               const float* __restrict__ ws,
                                               float* __restrict__ wsP) {
    __shared__ float As[K1_ROWS][K1_KC + 1];              // +1 pad: bank-safe
    __shared__ __align__(16) float Bs[K1_KC * WCOLS];     // 43 KB
    const float* wcatT = &ws[WS_WCAT];
    int tid = threadIdx.x;
    int b0  = blockIdx.x * K1_ROWS;
    int r   = tid >> 4;       // 0..15 row
    int cg  = tid & 15;       // 0..15 col group (12 cols each)
    float acc[12];
#pragma unroll
    for (int j = 0; j < 12; ++j) acc[j] = 0.f;

    for (int ks = 0; ks < SDIM; ks += K1_KC) {
        {   // stage A tile: 16 rows x 56
            int rr = tid >> 4, kk = tid & 15;
            for (int k2 = kk; k2 < K1_KC; k2 += 16)
                As[rr][k2] = states[(b0 + rr) * SDIM + ks + k2];
        }
        // stage B tile: contiguous 56*192 floats, float4 loads
        for (int i = tid * 4; i < K1_KC * WCOLS; i += 256 * 4) {
            float4 v = *reinterpret_cast<const float4*>(&wcatT[ks * WCOLS + i]);
            *reinterpret_cast<float4*>(&Bs[i]) = v;
        }
        __syncthreads();
#pragma unroll 4
        for (int kk = 0; kk < K1_KC; ++kk) {
            float a = As[r][kk];
            const float* bp = &Bs[kk * WCOLS + cg * 12];
#pragma unroll
            for (int j = 0; j < 12; ++j) acc[j] += a * bp[j];
        }
        __syncthreads();
    }
    float* outp = &wsP[WS_P + (b0 + r) * WCOLS + cg * 12];
#pragma unroll
    for (int j = 0; j < 12; ++j) outp[j] = acc[j];
}

// ---------------------------------------------------------------------------
// k2: one block per batch row.
// v5: layer-2 of the graph MLP runs on MFMA (split-bf16: h=hi+lo truncation
//     split, 3x mfma_f32_16x16x32_bf16 per tile, lo*lo dropped ~2^-16).
//     Per block: P[256][64] = H1[256][64] x W2T[64][64]; 4 waves x 4x4 tiles
//     x K=2. Accumulators (64 VGPR) can't be rematerialized -> no spill fight.
__global__ __launch_bounds__(256, 4) void k2_main(
    const float* __restrict__ agent_qs,
    const float* __restrict__ states,
    const int*   __restrict__ actions,
    const float* __restrict__ key_W,
    const float* __restrict__ wh_b,
    const float* __restrict__ V_b1,
    const float* __restrict__ V_W2,
    const float* __restrict__ V_b2,
    const float* __restrict__ g_b1,
    const float* __restrict__ g_W2,
    const float* __restrict__ g_b2,
    const float* __restrict__ g_W3,
    const float* __restrict__ g_b3,
    float* __restrict__ ws,
    float* __restrict__ out)
{
    const int b   = blockIdx.x;
    const int tid = threadIdx.x;

    __shared__ float unit_s[NAG * 33];               // padded stride 33
    __shared__ float sel_s[128];
    __shared__ float proj_s[HN * 33];
    __shared__ float attw_s[64];
    __shared__ __align__(16) float As[NAG * 68];     // stride 68 floats
    __shared__ __align__(16) float Bsh[NAG * 68];
    __shared__ float b1s[GHD];
    __shared__ float b2s[GHD], W3s[GHD];
    __shared__ float adjmean_s[NAG];
    __shared__ float qs_s[NAG];
    __shared__ float red_s[256];
    // W2 split-bf16, fragment-linear: hi at [((kt*4+nt)*64+l)*8+j], lo at +4096
    __shared__ __align__(16) unsigned short w2f_s[8192];   // 16 KB

    // ---- stage
    for (int i = tid; i < NAG * UDIM; i += 256)
        unit_s[(i >> 5) * 33 + (i & 31)] = states[b * SDIM + i];
    if (tid < 128) sel_s[tid] = ws[WS_P + b * WCOLS + tid];
    if (tid < GHD) { b1s[tid] = g_b1[tid]; b2s[tid] = g_b2[tid]; W3s[tid] = g_W3[tid]; }
    if (tid < NAG) qs_s[tid] = agent_qs[b * NAG + tid];
    // stage + split W2 into fragment-linear bf16 hi/lo
    for (int idx = tid; idx < 4096; idx += 256) {
        int j   = idx & 7;
        int li  = (idx >> 3) & 63;
        int ntk = idx >> 9;               // kt*4+nt
        int kt  = ntk >> 2, nt = ntk & 3;
        int g2  = nt * 16 + (li & 15);
        int g   = kt * 32 + (li >> 4) * 8 + j;
        float wv = g_W2[g2 * 64 + g];
        unsigned bits = __float_as_uint(wv);
        unsigned short hi = (unsigned short)(bits >> 16);
        float hf = __uint_as_float(bits & 0xffff0000u);
        float lo = wv - hf;               // exact residual
        unsigned short lob = (unsigned short)(__float_as_uint(lo) >> 16);
        w2f_s[idx] = hi;
        w2f_s[4096 + idx] = lob;
    }
    __syncthreads();

    // ---- proj[h][u] = sum_e sel[h,e] * key_W[h,e,u]
    if (tid < 128) {
        int h = tid >> 5, u = tid & 31;
        float a = 0.f;
#pragma unroll
        for (int e = 0; e < EDIM; ++e)
            a += sel_s[h * EDIM + e] * key_W[(h * EDIM + e) * UDIM + u];
        proj_s[h * 33 + u] = a;
    }
    // ---- A[i][g] = u_i . W1a[g] + b1[g] ;  B[j][g] = u_j . W1b[g]
    {
        const float* W1T = &ws[WS_W1T];
        for (int o = tid; o < 2 * NAG * GHD; o += 256) {
            int which = o >> 10;          // 0=A, 1=B
            int i = (o >> 6) & 15;
            int g = o & 63;
            float a = 0.f;
#pragma unroll
            for (int u = 0; u < UDIM; ++u)
                a += unit_s[i * 33 + u] * W1T[(which * UDIM + u) * 64 + g];
            if (which == 0) As[i * 68 + g] = a + b1s[g];
            else            Bsh[i * 68 + g] = a;
        }
    }
    __syncthreads();

    // ---- wave 0: logits + reg sumsq + masked softmax
    if (tid < 64) {
        int n = tid & 15;
        int h = tid >> 4;
        float l = 0.f;
#pragma unroll
        for (int u = 0; u < UDIM; ++u)
            l += proj_s[h * 33 + u] * unit_s[n * 33 + u];
        float sq = l * l;
#pragma unroll
        for (int m = 1; m < 64; m <<= 1) sq += __shfl_xor(sq, m, 64);
        if (tid == 0) ws[WS_PART + b * 8 + 0] = sq;
        float sc = l * 0.17677669529663688f;          // 1/sqrt(32)
        if (actions[b * NAG + n] == 0) sc = NEGV;
        float mx = sc;
#pragma unroll
        for (int m = 1; m < 16; m <<= 1) mx = fmaxf(mx, __shfl_xor(mx, m, 16));
        float ex = expf(sc - mx);
        float sm = ex;
#pragma unroll
        for (int m = 1; m < 16; m <<= 1) sm += __shfl_xor(sm, m, 16);
        attw_s[tid] = ex / sm;
    }

    // ---- pair phase on MFMA: P[256][64] = H1 x W2T, split-bf16
    {
        const int w   = tid >> 6;     // wave id: rows [64w, 64w+64)
        const int l   = tid & 63;
        const int lhi = l >> 4;       // 0..3
        const int llo = l & 15;       // 0..15

        f32x4 acc[4][4];
#pragma unroll
        for (int mt = 0; mt < 4; ++mt)
#pragma unroll
            for (int nt = 0; nt < 4; ++nt)
                acc[mt][nt] = (f32x4){0.f, 0.f, 0.f, 0.f};

#pragma unroll
        for (int kt = 0; kt < 2; ++kt) {
#pragma unroll
            for (int mt = 0; mt < 4; ++mt) {
                // A-frag: H1[p][g], p = 64w+16mt+(lane&15) -> As row 4w+mt
                // (wave-uniform), Bsh row = llo; g = kt*32 + lhi*8 + j.
                const int arow = 4 * w + mt;
                const int g0   = kt * 32 + lhi * 8;
                const float4* ap = reinterpret_cast<const float4*>(&As[arow * 68 + g0]);
                const float4* bp = reinterpret_cast<const float4*>(&Bsh[llo * 68 + g0]);
                float4 a0 = ap[0], a1 = ap[1], b0 = bp[0], b1 = bp[1];
                float hv[8];
                hv[0] = fmaxf(a0.x + b0.x, 0.f);
                hv[1] = fmaxf(a0.y + b0.y, 0.f);
                hv[2] = fmaxf(a0.z + b0.z, 0.f);
                hv[3] = fmaxf(a0.w + b0.w, 0.f);
                hv[4] = fmaxf(a1.x + b1.x, 0.f);
                hv[5] = fmaxf(a1.y + b1.y, 0.f);
                hv[6] = fmaxf(a1.z + b1.z, 0.f);
                hv[7] = fmaxf(a1.w + b1.w, 0.f);
                bf16x8 ahi, alo;
#pragma unroll
                for (int j = 0; j < 8; ++j) {
                    unsigned bits = __float_as_uint(hv[j]);
                    ahi[j] = (short)(bits >> 16);
                    float hf = __uint_as_float(bits & 0xffff0000u);
                    float lo = hv[j] - hf;
                    alo[j] = (short)(__float_as_uint(lo) >> 16);
                }
#pragma unroll
                for (int nt = 0; nt < 4; ++nt) {
                    const int fo = ((kt * 4 + nt) * 64 + l) * 8;
                    bf16x8 bhi = *reinterpret_cast<const bf16x8*>(&w2f_s[fo]);
                    bf16x8 blo = *reinterpret_cast<const bf16x8*>(&w2f_s[4096 + fo]);
                    acc[mt][nt] = __builtin_amdgcn_mfma_f32_16x16x32_bf16(ahi, bhi, acc[mt][nt], 0, 0, 0);
                    acc[mt][nt] = __builtin_amdgcn_mfma_f32_16x16x32_bf16(ahi, blo, acc[mt][nt], 0, 0, 0);
                    acc[mt][nt] = __builtin_amdgcn_mfma_f32_16x16x32_bf16(alo, bhi, acc[mt][nt], 0, 0, 0);
                }
            }
        }

        // epilogue: D layout col=lane&15, row=(lane>>4)*4+r  [m89/m91]
        const float gb3 = g_b3[0];
#pragma unroll
        for (int mt = 0; mt < 4; ++mt) {
            float part[4] = {0.f, 0.f, 0.f, 0.f};
#pragma unroll
            for (int nt = 0; nt < 4; ++nt) {
                const int g2 = nt * 16 + llo;
                const float b2v = b2s[g2], w3v = W3s[g2];
#pragma unroll
                for (int r = 0; r < 4; ++r)
                    part[r] += fmaxf(acc[mt][nt][r] + b2v, 0.f) * w3v;
            }
#pragma unroll
            for (int m = 1; m < 16; m <<= 1) {
#pragma unroll
                for (int r = 0; r < 4; ++r)
                    part[r] += __shfl_xor(part[r], m, 64);
            }
            if (llo == 0) {
#pragma unroll
                for (int r = 0; r < 4; ++r) {
                    const int p = 64 * w + 16 * mt + lhi * 4 + r;
                    float el = gb3 + part[r];
                    float adjv = 1.f / (1.f + expf(-el));
                    if ((p >> 4) == (p & 15)) adjv += 1.f;
                    out[4101 + b * 256 + p] = adjv;
                    red_s[p] = adjv;
                }
            }
        }
    }
    __syncthreads();

    // ---- adj_mean[j] = mean_i adj[i][j]
    if (tid < NAG) {
        float s = 0.f;
#pragma unroll
        for (int i = 0; i < NAG; ++i) s += red_s[i * NAG + tid];
        adjmean_s[tid] = s * (1.0f / 16.0f);
    }
    __syncthreads();

    // ---- renorm, head_q, entropy, q_tot pieces
    if (tid < 64) {
        int n = tid & 15;
        int h = tid >> 4;
        float a = attw_s[tid] * adjmean_s[n];
        float s = a;
#pragma unroll
        for (int m = 1; m < 16; m <<= 1) s += __shfl_xor(s, m, 16);
        float adjw = a / (s + 1e-8f);
        float hq  = qs_s[n] * adjw;
        float ent = -logf(adjw + 1e-8f) * adjw;
#pragma unroll
        for (int m = 1; m < 16; m <<= 1) {
            hq  += __shfl_xor(hq, m, 16);
            ent += __shfl_xor(ent, m, 16);
        }
        if (n == 0) {
            float wh = fabsf(ws[WS_P + b * WCOLS + 160 + h] + wh_b[h]);
            red_s[h] = wh * hq;
            ws[WS_PART + b * 8 + 1 + h] = ent;
        }
    }
    __syncthreads();
    if (tid == 0) {
        float v = V_b2[0];
#pragma unroll
        for (int e = 0; e < EDIM; ++e)
            v += fmaxf(ws[WS_P + b * WCOLS + 128 + e] + V_b1[e], 0.f) * V_W2[e];
        out[b] = red_s[0] + red_s[1] + red_s[2] + red_s[3] + v;
    }
}

// ---------------------------------------------------------------------------
// k3: deterministic final reduction of partials -> attend_mag_regs, head_entropies
__global__ __launch_bounds__(256) void k3_final(const float* __restrict__ ws,
                                                float* __restrict__ out) {
    __shared__ float red[4][5];
    int tid = threadIdx.x;
    float acc[5] = {0.f, 0.f, 0.f, 0.f, 0.f};
    for (int r = tid; r < NBATCH; r += 256) {
        const float* p = &ws[WS_PART + r * 8];
#pragma unroll
        for (int j = 0; j < 5; ++j) acc[j] += p[j];
    }
#pragma unroll
    for (int j = 0; j < 5; ++j) {
        float v = acc[j];
#pragma unroll
        for (int m = 1; m < 64; m <<= 1) v += __shfl_xor(v, m, 64);
        if ((tid & 63) == 0) red[tid >> 6][j] = v;
    }
    __syncthreads();
    if (tid == 0) {
        float s0 = red[0][0] + red[1][0] + red[2][0] + red[3][0];
        out[4096] = s0 * (COEF / 65536.0f);          // mean over B*N, sum over H
#pragma unroll
        for (int h = 0; h < 4; ++h) {
            float s = red[0][1 + h] + red[1][1 + h] + red[2][1 + h] + red[3][1 + h];
            out[4097 + h] = s * (1.0f / 4096.0f);    // mean over B
        }
    }
}

// ---------------------------------------------------------------------------
extern "C" void kernel_launch(void* const* d_in, const int* in_sizes, int n_in,
                              void* d_out, int out_size, void* d_ws, size_t ws_size,
                              hipStream_t stream) {
    const float* agent_qs = (const float*)d_in[0];
    const float* states   = (const float*)d_in[1];
    const int*   actions  = (const int*)  d_in[2];
    const float* sel_W    = (const float*)d_in[3];
    const float* key_W    = (const float*)d_in[4];
    const float* wh_W     = (const float*)d_in[5];
    const float* wh_b     = (const float*)d_in[6];
    const float* V_W1     = (const float*)d_in[7];
    const float* V_b1     = (const float*)d_in[8];
    const float* V_W2     = (const float*)d_in[9];
    const float* V_b2     = (const float*)d_in[10];
    const float* g_W1     = (const float*)d_in[11];
    const float* g_b1     = (const float*)d_in[12];
    const float* g_W2     = (const float*)d_in[13];
    const float* g_b2     = (const float*)d_in[14];
    const float* g_W3     = (const float*)d_in[15];
    const float* g_b3     = (const float*)d_in[16];

    float* ws  = (float*)d_ws;
    float* out = (float*)d_out;

    // k0: weight transposes (111,616 elements)
    k0_prep<<<436, 256, 0, stream>>>(sel_W, V_W1, wh_W, g_W1, ws);
    // k1: skinny GEMM [4096,560]x[560,192]
    k1_gemm<<<NBATCH / K1_ROWS, 256, 0, stream>>>(states, ws, ws);
    // k2: per-row fused mixer + graph MLP (MFMA layer-2)
    k2_main<<<NBATCH, 256, 0, stream>>>(agent_qs, states, actions, key_W,
                                        wh_b, V_b1, V_W2, V_b2,
                                        g_b1, g_W2, g_b2, g_W3, g_b3,
                                        ws, out);
    // k3: scalar outputs
    k3_final<<<1, 256, 0, stream>>>(ws, out);
}